// Round 4
// baseline (508.391 us; speedup 1.0000x reference)
//
#include <hip/hip_runtime.h>

#define U_    128
#define DIN   10240
#define RANK  320
#define NS    32
#define NTOT  384          // 320 (t) + 32 (B) + 32 (C)
#define KC    32           // k-split count in gemm1
#define KCH   (DIN / KC)   // 320 k per chunk

// float4 helpers
__device__ __forceinline__ void fma4(float4& a, const float4& v, float s) {
    a.x += v.x * s; a.y += v.y * s; a.z += v.z * s; a.w += v.w * s;
}

// -------------------------------------------------------------------------
// Kernel 0: transpose x[128,10240] -> xT[10240,128] (coalesced GEMM loads).
// -------------------------------------------------------------------------
__global__ __launch_bounds__(256) void transpose_kernel(
    const float* __restrict__ x, float* __restrict__ xT)
{
    __shared__ float tile[32][33];
    int kb = blockIdx.x * 32, ub = blockIdx.y * 32;
    int tx = threadIdx.x, ty = threadIdx.y;      // (32, 8)
#pragma unroll
    for (int i = 0; i < 32; i += 8)
        tile[ty + i][tx] = x[(size_t)(ub + ty + i) * DIN + kb + tx];
    __syncthreads();
#pragma unroll
    for (int i = 0; i < 32; i += 8)
        xT[(size_t)(kb + ty + i) * U_ + ub + tx] = tile[tx][ty + i];
}

// -------------------------------------------------------------------------
// Kernel 1: streaming register-tiled GEMM, no LDS.
// partial[kc][n][u] = sum_{k in chunk} xT[k,u] * W[k,n], n in [0,384).
// Block = 256 thr: 32 u-groups x 8 n-groups, each thread a 4u x 4n tile.
// Per k-iter/thread: 1 float4 xT load (coalesced 512B/wave) +
//                    1 float4 W load + 16 fma. unroll 8 => 16-load window.
// Grid 12 nt x 32 kc = 384 blocks = 1536 waves.
// -------------------------------------------------------------------------
__global__ __launch_bounds__(256) void gemm1_kernel(
    const float* __restrict__ xT,
    const float* __restrict__ Wd, const float* __restrict__ Wb,
    const float* __restrict__ Wc,
    float* __restrict__ partial)
{
    int b  = blockIdx.x;
    int nt = b % 12;
    int kc = b / 12;
    int ug = threadIdx.x & 31;       // 4 consecutive u
    int ng = threadIdx.x >> 5;       // 4 consecutive n

    const float* W; int ldw, c0, nbase;
    if (nt < 10)       { W = Wd; ldw = RANK; c0 = nt * 32; nbase = nt * 32; }
    else if (nt == 10) { W = Wb; ldw = NS;   c0 = 0;       nbase = 320;     }
    else               { W = Wc; ldw = NS;   c0 = 0;       nbase = 352;     }

    int k0 = kc * KCH;
    const float* xp = xT + (size_t)k0 * U_ + 4 * ug;
    const float* wp = W  + (size_t)k0 * ldw + c0 + 4 * ng;

    float4 acc0 = {0,0,0,0}, acc1 = {0,0,0,0}, acc2 = {0,0,0,0}, acc3 = {0,0,0,0};

#pragma unroll 8
    for (int k = 0; k < KCH; ++k) {
        float4 xv = *(const float4*)(xp + (size_t)k * U_);
        float4 wv = *(const float4*)(wp + (size_t)k * ldw);
        fma4(acc0, xv, wv.x);
        fma4(acc1, xv, wv.y);
        fma4(acc2, xv, wv.z);
        fma4(acc3, xv, wv.w);
    }

    // FIX (R3 bug): n index is nbase + 4*ng, computed once, no double-add.
    float* out = partial + ((size_t)kc * NTOT + nbase + 4 * ng) * U_ + 4 * ug;
    *(float4*)(out)          = acc0;
    *(float4*)(out + U_)     = acc1;
    *(float4*)(out + 2 * U_) = acc2;
    *(float4*)(out + 3 * U_) = acc3;
}

// -------------------------------------------------------------------------
// Kernel 2: reduce 32 k-chunk partials -> tT[320,128], B[128,32], C[128,32].
// -------------------------------------------------------------------------
__global__ __launch_bounds__(256) void reduce_kernel(
    const float* __restrict__ partial, float* __restrict__ tT,
    float* __restrict__ Bc, float* __restrict__ Cc)
{
    int e = blockIdx.x * 256 + threadIdx.x;      // 0..49151
    float s = 0.f;
#pragma unroll 8
    for (int kc = 0; kc < KC; ++kc)
        s += partial[(size_t)kc * (NTOT * U_) + e];
    int n = e >> 7, u = e & 127;                 // e = n*128 + u
    if (n < RANK)            tT[e] = s;
    else if (n < RANK + NS)  Bc[u * NS + (n - RANK)] = s;
    else                     Cc[u * NS + (n - RANK - NS)] = s;
}

// -------------------------------------------------------------------------
// Kernel 3: delta = softplus(t @ W_dt + b_dt), streaming register-tiled.
// Block = 256 thr: 32 d-groups x 8 u-groups, thread = 4d x 4u tile.
// Grid 80 dt x 4 ut = 320 blocks = 1280 waves.
// -------------------------------------------------------------------------
__global__ __launch_bounds__(256) void gemm2_kernel(
    const float* __restrict__ tT, const float* __restrict__ Wdt,
    const float* __restrict__ b_dt, float* __restrict__ delta)
{
    int b   = blockIdx.x;
    int dt_ = b % 80, ut = b / 80;
    int dg = threadIdx.x & 31, ug = threadIdx.x >> 5;
    int d0 = dt_ * 128 + 4 * dg;
    int u0 = ut * 32 + 4 * ug;

    float4 bias = *(const float4*)(b_dt + d0);
    float4 acc0 = bias, acc1 = bias, acc2 = bias, acc3 = bias;  // acc_i: u = u0+i

    const float* wp = Wdt + d0;
    const float* tp = tT + u0;

#pragma unroll 8
    for (int r = 0; r < RANK; ++r) {
        float4 wv = *(const float4*)(wp + (size_t)r * DIN);
        float4 tv = *(const float4*)(tp + (size_t)r * U_);
        fma4(acc0, wv, tv.x);
        fma4(acc1, wv, tv.y);
        fma4(acc2, wv, tv.z);
        fma4(acc3, wv, tv.w);
    }

    float4 a[4] = {acc0, acc1, acc2, acc3};
#pragma unroll
    for (int i = 0; i < 4; ++i) {
        float4 z = a[i];
        float4 sp;
        sp.x = (z.x > 20.f) ? z.x : log1pf(__expf(z.x));
        sp.y = (z.y > 20.f) ? z.y : log1pf(__expf(z.y));
        sp.z = (z.z > 20.f) ? z.z : log1pf(__expf(z.z));
        sp.w = (z.w > 20.f) ? z.w : log1pf(__expf(z.w));
        *(float4*)(delta + (size_t)(u0 + i) * DIN + d0) = sp;
    }
}

// -------------------------------------------------------------------------
// Kernel 4: state update (memory-bound, ~353 MB HBM). Unchanged from R1/R2.
// -------------------------------------------------------------------------
__global__ __launch_bounds__(256) void ssm_kernel(
    const float* __restrict__ x, const float* __restrict__ h,
    const float* __restrict__ delta,
    const float* __restrict__ Bc, const float* __restrict__ Cc,
    const float* __restrict__ A, const float* __restrict__ Dvec,
    float* __restrict__ y, float* __restrict__ hnew)
{
    int idx4 = blockIdx.x * 256 + threadIdx.x;   // float4 index
    int n4 = idx4 & 7;
    int ud = idx4 >> 3;
    int d = ud % DIN;
    int u = ud / DIN;

    float dlt = delta[ud];
    float xv  = x[ud];

    float4 hv = ((const float4*)h)[idx4];
    float4 av = ((const float4*)A)[(size_t)d * 8 + n4];
    float4 bv = ((const float4*)Bc)[u * 8 + n4];
    float4 cv = ((const float4*)Cc)[u * 8 + n4];

    float dx = dlt * xv;
    float4 hn;
    hn.x = __expf(dlt * av.x) * hv.x + dx * bv.x;
    hn.y = __expf(dlt * av.y) * hv.y + dx * bv.y;
    hn.z = __expf(dlt * av.z) * hv.z + dx * bv.z;
    hn.w = __expf(dlt * av.w) * hv.w + dx * bv.w;

    ((float4*)hnew)[idx4] = hn;

    float p = hn.x * cv.x + hn.y * cv.y + hn.z * cv.z + hn.w * cv.w;
    p += __shfl_xor(p, 4, 8);
    p += __shfl_xor(p, 2, 8);
    p += __shfl_xor(p, 1, 8);
    if (n4 == 0)
        y[ud] = p + Dvec[d] * xv;
}

// -------------------------------------------------------------------------
extern "C" void kernel_launch(void* const* d_in, const int* in_sizes, int n_in,
                              void* d_out, int out_size, void* d_ws, size_t ws_size,
                              hipStream_t stream)
{
    const float* x   = (const float*)d_in[0];
    const float* h   = (const float*)d_in[1];
    const float* Wd  = (const float*)d_in[2];
    const float* Wdt = (const float*)d_in[3];
    const float* bdt = (const float*)d_in[4];
    const float* Wb  = (const float*)d_in[5];
    const float* Wc  = (const float*)d_in[6];
    const float* A   = (const float*)d_in[7];
    const float* Dv  = (const float*)d_in[8];

    float* ws      = (float*)d_ws;
    float* xT      = ws;                       // 10240*128       = 1310720
    float* partial = ws + 1310720;             // 32*384*128      = 1572864
    float* delta   = partial;                  // ALIAS: partial dead after reduce
    float* tT      = ws + 1310720 + 1572864;   // 320*128         = 40960
    float* Bc      = tT + 40960;               // 128*32          = 4096
    float* Cc      = Bc + 4096;                // 128*32          = 4096
    // total ws use: 2932736 floats = 11.73 MB

    float* y    = (float*)d_out;               // [128,10240]
    float* hnew = y + (size_t)U_ * DIN;        // [128,10240,32]

    dim3 tb(32, 8);
    transpose_kernel<<<dim3(DIN / 32, U_ / 32), tb, 0, stream>>>(x, xT);
    gemm1_kernel    <<<384, 256, 0, stream>>>(xT, Wd, Wb, Wc, partial);
    reduce_kernel   <<<192, 256, 0, stream>>>(partial, tT, Bc, Cc);
    gemm2_kernel    <<<320, 256, 0, stream>>>(tT, Wdt, bdt, delta);
    ssm_kernel      <<<40960, 256, 0, stream>>>(x, h, delta, Bc, Cc, A, Dv, y, hnew);
}